// Round 6
// baseline (1480.923 us; speedup 1.0000x reference)
//
#include <hip/hip_runtime.h>
#include <stdint.h>

#define B_SZ 16384
#define D_SZ 1024
#define F_SZ 8192
#define K_TOP 30
#define N_CAND 46     // histogram threshold rank (superset margin for exact rerank)
#define CAND_CAP 64   // max candidates kept per row
#define NBUCK 8192    // histogram bins
#define NSLICE 8      // feature slices (1024 features = 4 MB fp32 each = one XCD L2)

typedef short bf16x8 __attribute__((ext_vector_type(8)));
typedef ushort u16x8 __attribute__((ext_vector_type(8)));
typedef float f32x4 __attribute__((ext_vector_type(4)));
typedef uint32_t u32x4 __attribute__((ext_vector_type(4)));

// round-to-nearest-even float -> bf16 bits
__device__ __forceinline__ ushort f2bf(float f) {
  union { float f; uint32_t u; } a;
  a.f = f;
  const uint32_t r = a.u + 0x7fffu + ((a.u >> 16) & 1u);
  return (ushort)(r >> 16);
}

__device__ __forceinline__ float bf2f(ushort h) {
  union { uint32_t u; float f; } c;
  c.u = (uint32_t)h << 16;
  return c.f;
}

__device__ __forceinline__ void async16(const void* g, void* l) {
  __builtin_amdgcn_global_load_lds(
      (const __attribute__((address_space(1))) uint32_t*)g,
      (__attribute__((address_space(3))) uint32_t*)l, 16, 0, 0);
}

__device__ __forceinline__ void stnt4(void* p, float4 v) {
  union { float4 f; u32x4 u; } c;
  c.f = v;
  __builtin_nontemporal_store(c.u, (u32x4*)p);
}

// monotone value->bucket map: width 1/512 over [-8, 8]
__device__ __forceinline__ int bk(float f) {
  int k = (int)floorf(f * 512.f) + 4096;
  k = k < 0 ? 0 : k;
  return k > (NBUCK - 1) ? (NBUCK - 1) : k;
}

// ---------------------------------------------------------------------------
// Convert (x - dec_b) -> bf16 and enc_w -> bf16 in one launch.
// Blocks [0, NXB) do x; blocks [NXB, NXB+NWB) do enc_w. Exact multiples of
// 256 float4s -> every block is branch-uniform.
// ---------------------------------------------------------------------------
#define NXB (B_SZ * D_SZ / 4 / 256)
#define NWB (F_SZ * D_SZ / 4 / 256)

__global__ __launch_bounds__(256) void conv_xw(const float* __restrict__ x,
                                               const float* __restrict__ w,
                                               const float* __restrict__ dec_b,
                                               ushort* __restrict__ xh,
                                               ushort* __restrict__ wh) {
  if (blockIdx.x < NXB) {
    const int i = blockIdx.x * 256 + threadIdx.x;
    const float4 v = ((const float4*)x)[i];
    const float4 db = ((const float4*)dec_b)[i & (D_SZ / 4 - 1)];
    ushort4 o;
    o.x = f2bf(v.x - db.x);
    o.y = f2bf(v.y - db.y);
    o.z = f2bf(v.z - db.z);
    o.w = f2bf(v.w - db.w);
    ((ushort4*)xh)[i] = o;
  } else {
    const int i = (blockIdx.x - NXB) * 256 + threadIdx.x;
    const float4 v = ((const float4*)w)[i];
    ushort4 o;
    o.x = f2bf(v.x);
    o.y = f2bf(v.y);
    o.z = f2bf(v.z);
    o.w = f2bf(v.w);
    ((ushort4*)wh)[i] = o;
  }
}

// ---------------------------------------------------------------------------
// Approx encode GEMM (bf16 MFMA, m97 structure), 128x128 tile, BK=64.
// Half the barrier/drain count of BK=32; LDS stays 32 KB (under the 64 KB
// occupancy cliff). Both-sides XOR chunk swizzle (rule #21): staging source
// chunk = c ^ (r&7) with linear global_load_lds dest; fragment reads chunk
// kc ^ (row&7). Balanced 8 lanes/bank-quad, distinct addrs = b128 floor.
// Epilogue transposes each wave's 64x64 C-subtile through LDS (aliases the
// staging buffers) so global stores are contiguous 16B chunks.
// ---------------------------------------------------------------------------
#define GBM 128
#define GBN 128
#define GBK 64
#define EPI_STRIDE 72  // 64 + 8 pad

__global__ __launch_bounds__(256) void encode_gemm_bf16(
    const ushort* __restrict__ A, const ushort* __restrict__ W,
    const float* __restrict__ enc_b, ushort* __restrict__ pre) {
  __shared__ ushort smem[2 * GBM * GBK];  // 32 KB; epi (18 KB) aliases
  ushort* As = smem;              // [128][64] (chunk-swizzled)
  ushort* Bs = smem + GBM * GBK;
  const int tid = threadIdx.x;
  const int wave = tid >> 6;
  const int lane = tid & 63;
  const int rb = blockIdx.y * GBM;
  const int cb = blockIdx.x * GBN;
  const int wm = (wave >> 1) * 64;
  const int wn = (wave & 1) * 64;

  // staging: thread t covers row r = (t>>3) + 32*i, chunk c = t&7 (16B).
  // source chunk is inverse-swizzled: csrc = c ^ (r&7); r&7 == (t>>3)&7 for
  // all rounds i (32*i == 0 mod 8), so csrc is per-thread constant.
  const int sr = tid >> 3;
  const int csrc = ((tid & 7) ^ (sr & 7)) * 8;  // ushort offset in row
  const ushort* gA = A + (size_t)(rb + sr) * D_SZ + csrc;
  const ushort* gB = W + (size_t)(cb + sr) * D_SZ + csrc;

  f32x4 acc[4][4];
#pragma unroll
  for (int i = 0; i < 4; i++)
#pragma unroll
    for (int j = 0; j < 4; j++) acc[i][j] = (f32x4)(0.f);

  const int fm = lane & 15;
  const int kq = lane >> 4;  // k-quarter 0..3

  for (int kt = 0; kt < D_SZ; kt += GBK) {
    __syncthreads();
#pragma unroll
    for (int i = 0; i < 4; i++) {
      async16(gA + (size_t)(32 * i) * D_SZ + kt, &As[i * 2048 + wave * 512]);
      async16(gB + (size_t)(32 * i) * D_SZ + kt, &Bs[i * 2048 + wave * 512]);
    }
    __syncthreads();
#pragma unroll
    for (int kk = 0; kk < 2; kk++) {
      const int kc = (kk << 2) | kq;  // logical 16B chunk within row
      bf16x8 af[4], bfr[4];
#pragma unroll
      for (int i = 0; i < 4; i++) {
        const int row = wm + i * 16 + fm;
        af[i] = *(const bf16x8*)&As[row * GBK + (kc ^ (fm & 7)) * 8];
      }
#pragma unroll
      for (int j = 0; j < 4; j++) {
        const int row = wn + j * 16 + fm;
        bfr[j] = *(const bf16x8*)&Bs[row * GBK + (kc ^ (fm & 7)) * 8];
      }
#pragma unroll
      for (int i = 0; i < 4; i++)
#pragma unroll
        for (int j = 0; j < 4; j++)
          acc[i][j] = __builtin_amdgcn_mfma_f32_16x16x32_bf16(af[i], bfr[j],
                                                              acc[i][j], 0, 0, 0);
    }
  }

  // ---- epilogue: LDS transpose -> contiguous bf16 rows, 16B stores ----
  __syncthreads();  // all waves done reading As/Bs before epi clobbers them
  float eb[4];
#pragma unroll
  for (int j = 0; j < 4; j++) eb[j] = enc_b[cb + wn + j * 16 + fm];

  ushort* epi = &smem[wave * 32 * EPI_STRIDE];  // 32 rows x 72 ushorts
  const int rg = lane >> 4;  // row group 0..3
  const int rr = lane & 31;
  const int cc = (lane >> 5) * 4;
#pragma unroll
  for (int p = 0; p < 2; p++) {
    // C layout: row_local = wm + (2p+i2)*16 + rg*4 + r, col_local = wn + j*16 + fm
#pragma unroll
    for (int i2 = 0; i2 < 2; i2++) {
      const int i = p * 2 + i2;
#pragma unroll
      for (int j = 0; j < 4; j++)
#pragma unroll
        for (int r = 0; r < 4; r++)
          epi[(i2 * 16 + rg * 4 + r) * EPI_STRIDE + j * 16 + fm] =
              f2bf(acc[i][j][r] + eb[j]);
    }
    // read back row-major; wave-private region (per-wave in-order DS pipe)
    ushort* gp = pre + (size_t)(rb + wm + p * 32 + rr) * F_SZ + cb + wn + cc * 8;
#pragma unroll
    for (int c = 0; c < 4; c++) {
      const u16x8 d = *(const u16x8*)&epi[rr * EPI_STRIDE + (cc + c) * 8];
      *(u16x8*)(gp + c * 8) = d;  // regular store: L2 merges full lines
    }
  }
}

// ---------------------------------------------------------------------------
// Histogram top-candidate select per row (bf16 pre input). Collects ALL
// indices whose approx value lands at-or-above the bucket where the top-down
// cumulative count reaches N_CAND (superset of approx top-N_CAND). Also bins
// candidates into per-feature-slice lists (packed f | gpos<<13).
// ---------------------------------------------------------------------------
__global__ __launch_bounds__(256) void topk_hist(const ushort* __restrict__ pre,
                                                 int* __restrict__ cidx,
                                                 int* __restrict__ ccnt,
                                                 int* __restrict__ scnt_g,
                                                 int* __restrict__ slists) {
  __shared__ uint32_t hist[NBUCK];  // 32 KB
  __shared__ int scan[256];
  __shared__ int Tsh;
  __shared__ int cnt;
  __shared__ int cand[CAND_CAP];
  __shared__ int scnt_sh[NSLICE];
  const int b = blockIdx.x;
  const int t = threadIdx.x;
  const ushort* prow = pre + (size_t)b * F_SZ;

#pragma unroll
  for (int q = 0; q < NBUCK / 256; q++) hist[q * 256 + t] = 0;
  if (t == 0) cnt = 0;
  if (t < NSLICE) scnt_sh[t] = 0;
  __syncthreads();

  // row in registers: thread t holds ushort8 chunks (q*256+t), 32 values
  u16x8 v[4];
#pragma unroll
  for (int q = 0; q < 4; q++) v[q] = ((const u16x8*)prow)[q * 256 + t];

  int bki[32];
#pragma unroll
  for (int q = 0; q < 4; q++)
#pragma unroll
    for (int e = 0; e < 8; e++) bki[q * 8 + e] = bk(bf2f(v[q][e]));

#pragma unroll
  for (int i = 0; i < 32; i++) atomicAdd(&hist[bki[i]], 1u);
  __syncthreads();

  // thread t owns a descending 32-bucket chunk; partial sums + inclusive scan
  const int cbase = NBUCK - 32 * (t + 1);
  int s = 0;
#pragma unroll
  for (int j = 0; j < 32; j++) s += (int)hist[cbase + j];
  scan[t] = s;
  __syncthreads();
  for (int off = 1; off < 256; off <<= 1) {
    const int add = (t >= off) ? scan[t - off] : 0;
    __syncthreads();
    scan[t] += add;
    __syncthreads();
  }
  const int incl = scan[t];
  const int excl = incl - s;
  if (excl < N_CAND && incl >= N_CAND) {  // unique crossing thread
    int cum = excl;
    int T = cbase;
    for (int j = 31; j >= 0; j--) {
      cum += (int)hist[cbase + j];
      if (cum >= N_CAND) { T = cbase + j; break; }
    }
    Tsh = T;
  }
  __syncthreads();
  const int T = Tsh;

  // collect candidates >= threshold bucket
#pragma unroll
  for (int q = 0; q < 4; q++)
#pragma unroll
    for (int e = 0; e < 8; e++) {
      if (bki[q * 8 + e] >= T) {
        const int p = atomicAdd(&cnt, 1);
        if (p < CAND_CAP) cand[p] = (q * 256 + t) * 8 + e;
      }
    }
  __syncthreads();
  const int C = cnt < CAND_CAP ? cnt : CAND_CAP;
  if (t == 0) ccnt[b] = C;
  if (t < C) {
    const int f = cand[t];
    cidx[(size_t)b * CAND_CAP + t] = f;
    const int sl = f >> 10;  // feature slice (1024 features each)
    const int p = atomicAdd(&scnt_sh[sl], 1);
    slists[((size_t)b * NSLICE + sl) * CAND_CAP + p] = f | (t << 13);
  }
  __syncthreads();
  if (t < NSLICE) scnt_g[b * NSLICE + t] = scnt_sh[t];
}

// ---------------------------------------------------------------------------
// Zero the sparse output (runs after topk_hist has consumed the bf16 pre
// that aliases this region; before rerank_finish scatters winners).
// ---------------------------------------------------------------------------
__global__ __launch_bounds__(256) void zero_sparse(float4* __restrict__ p) {
  const size_t n = (size_t)B_SZ * F_SZ / 4;
  const size_t stride = (size_t)gridDim.x * 256;
  for (size_t i = (size_t)blockIdx.x * 256 + threadIdx.x; i < n; i += stride)
    stnt4(&p[i], make_float4(0.f, 0.f, 0.f, 0.f));
}

// ---------------------------------------------------------------------------
// Sliced exact rerank: block bid = q*8 + s handles rows 4q..4q+3 (one wave
// each), feature slice s. With round-robin bid%8 -> XCD mapping, XCD s only
// gathers enc_w[s*1024 .. s*1024+1023] = 4 MB = its own L2. x rows are
// regular loads (64 MB total; L3-resident across the 8 slice re-reads).
// ---------------------------------------------------------------------------
__global__ __launch_bounds__(256) void rerank_slice(
    const float* __restrict__ x, const float* __restrict__ enc_w,
    const float* __restrict__ enc_b, const float* __restrict__ dec_b,
    const int* __restrict__ scnt_g, const int* __restrict__ slists,
    float* __restrict__ cv) {
  const int q = blockIdx.x >> 3;
  const int s = blockIdx.x & 7;
  const int wave = threadIdx.x >> 6;
  const int lane = threadIdx.x & 63;
  const int r = q * 4 + wave;

  const int cell = r * NSLICE + s;
  const int n = scnt_g[cell];
  if (n == 0) return;

  // x row minus dec_b, lane-interleaved float4s: xr[j] = row float4 (j*64+lane)
  float4 xr[4];
  {
    const float4* xp = (const float4*)(x + (size_t)r * D_SZ);
    const float4* dp = (const float4*)dec_b;
#pragma unroll
    for (int j = 0; j < 4; j++) {
      const float4 xv = xp[j * 64 + lane];
      const float4 db = dp[j * 64 + lane];
      xr[j] = make_float4(xv.x - db.x, xv.y - db.y, xv.z - db.z, xv.w - db.w);
    }
  }

  const int base = cell * CAND_CAP;
  int k = 0;
  while (k < n) {
    const int e0 = slists[base + k];
    const bool two = (k + 1) < n;
    const int e1 = two ? slists[base + k + 1] : e0;
    const int f0 = e0 & 8191, g0 = e0 >> 13;
    const int f1 = e1 & 8191, g1 = e1 >> 13;
    const float4* w0 = (const float4*)(enc_w + (size_t)f0 * D_SZ);
    const float4* w1 = (const float4*)(enc_w + (size_t)f1 * D_SZ);
    float a0 = 0.f, a1 = 0.f;
#pragma unroll
    for (int j = 0; j < 4; j++) {
      const float4 u = w0[j * 64 + lane];
      const float4 p = xr[j];
      a0 += u.x * p.x + u.y * p.y + u.z * p.z + u.w * p.w;
    }
#pragma unroll
    for (int j = 0; j < 4; j++) {
      const float4 u = w1[j * 64 + lane];
      const float4 p = xr[j];
      a1 += u.x * p.x + u.y * p.y + u.z * p.z + u.w * p.w;
    }
#pragma unroll
    for (int off = 32; off > 0; off >>= 1) {
      a0 += __shfl_xor(a0, off);
      a1 += __shfl_xor(a1, off);
    }
    if (lane == 0) {
      cv[(size_t)r * CAND_CAP + g0] = a0 + enc_b[f0];
      if (two) cv[(size_t)r * CAND_CAP + g1] = a1 + enc_b[f1];
    }
    k += 2;
  }
}

// ---------------------------------------------------------------------------
// Selection: one wave per row, bitonic sort 64 (value desc, idx asc), write
// top-30 + scatter relu'd exact values into sparse.
// ---------------------------------------------------------------------------
__global__ __launch_bounds__(64) void rerank_finish(
    const int* __restrict__ cidx, const int* __restrict__ ccnt,
    const float* __restrict__ cv, float* __restrict__ sparse,
    float* __restrict__ tkv, int* __restrict__ tki) {
  const int b = blockIdx.x;
  const int t = threadIdx.x;
  const int C = ccnt[b];
  float v = (t < C) ? cv[(size_t)b * CAND_CAP + t] : -__builtin_inff();
  int id = (t < C) ? cidx[(size_t)b * CAND_CAP + t] : 0x7fffffff;
#pragma unroll
  for (int k = 2; k <= 64; k <<= 1) {
#pragma unroll
    for (int j = k >> 1; j > 0; j >>= 1) {
      const float ov = __shfl_xor(v, j);
      const int oi = __shfl_xor(id, j);
      const bool up = (t & k) == 0;       // this block sorts best-first
      const bool lower = (t & j) == 0;    // lane is lower index of the pair
      const bool ob = (ov > v) || (ov == v && oi < id);  // other is better
      if ((lower == up) ? ob : !ob) { v = ov; id = oi; }
    }
  }
  if (t < K_TOP) {
    const float rv = v > 0.f ? v : 0.f;
    tkv[(size_t)b * K_TOP + t] = rv;
    tki[(size_t)b * K_TOP + t] = id;
    sparse[(size_t)b * F_SZ + id] = rv;
  }
}

// ---------------------------------------------------------------------------
// Transpose dec_w [D, F] -> dec_wT [F, D]
// ---------------------------------------------------------------------------
__global__ __launch_bounds__(256) void transpose_kernel(const float* __restrict__ in,
                                                        float* __restrict__ out) {
  __shared__ float tile[32][33];
  const int bx = blockIdx.x * 32;
  const int by = blockIdx.y * 32;
  const int tx = threadIdx.x & 31;
  const int ty = threadIdx.x >> 5;
#pragma unroll
  for (int r = 0; r < 32; r += 8)
    tile[ty + r][tx] = in[(size_t)(by + ty + r) * F_SZ + bx + tx];
  __syncthreads();
#pragma unroll
  for (int r = 0; r < 32; r += 8)
    out[(size_t)(bx + ty + r) * D_SZ + by + tx] = tile[tx][ty + r];
}

// ---------------------------------------------------------------------------
// Decode, XCD-sliced: block bid = g*8 + s computes rows g*8..g*8+7, columns
// s*128..s*128+127. XCD s only gathers the 512B column-chunk of each dec_wT
// row belonging to slice s -> 4 MB resident working set per XCD L2.
// ---------------------------------------------------------------------------
__global__ __launch_bounds__(256) void decode_kernel(const float* __restrict__ tkv,
                                                     const int* __restrict__ tki,
                                                     const float* __restrict__ dec_wT,
                                                     const float* __restrict__ dec_b,
                                                     float* __restrict__ recon) {
  __shared__ float kv[8][32];
  __shared__ int ki[8][32];
  const int g = blockIdx.x >> 3;
  const int s = blockIdx.x & 7;
  const int t = threadIdx.x;
  if (t < 8 * K_TOP) {
    const int rr = t / K_TOP;
    const int kk = t - rr * K_TOP;
    kv[rr][kk] = tkv[(size_t)(g * 8 + rr) * K_TOP + kk];
    ki[rr][kk] = tki[(size_t)(g * 8 + rr) * K_TOP + kk];
  }
  __syncthreads();
  const int rr = t >> 5;                 // 0..7 (row within group)
  const int col = s * 128 + (t & 31) * 4;
  const int b = g * 8 + rr;
  float4 acc = *(const float4*)&dec_b[col];
#pragma unroll 5
  for (int k = 0; k < K_TOP; k++) {
    const float v = kv[rr][k];
    const float4 w = *(const float4*)&dec_wT[(size_t)ki[rr][k] * D_SZ + col];
    acc.x += v * w.x; acc.y += v * w.y; acc.z += v * w.z; acc.w += v * w.w;
  }
  stnt4(&recon[(size_t)b * D_SZ + col], acc);
}

// ---------------------------------------------------------------------------
extern "C" void kernel_launch(void* const* d_in, const int* in_sizes, int n_in,
                              void* d_out, int out_size, void* d_ws, size_t ws_size,
                              hipStream_t stream) {
  const float* x     = (const float*)d_in[0];  // [B, D]
  const float* enc_w = (const float*)d_in[1];  // [F, D]
  const float* enc_b = (const float*)d_in[2];  // [F]
  const float* dec_w = (const float*)d_in[3];  // [D, F]
  const float* dec_b = (const float*)d_in[4];  // [D]

  float* recon_out  = (float*)d_out;                        // [B, D]
  float* sparse_out = (float*)d_out + (size_t)B_SZ * D_SZ;  // [B, F]

  // bf16 limbs live in the recon region (dead until decode, which runs last)
  ushort* xh = (ushort*)recon_out;        // [B, D] bf16 (32 MB)
  ushort* wh = xh + (size_t)B_SZ * D_SZ;  // [F, D] bf16 (16 MB)

  // bf16 pre-activations alias the sparse region (256 MB of its 512 MB);
  // consumed by topk_hist, then zero_sparse wipes the whole region before
  // rerank_finish scatters the winners.
  ushort* pre_h = (ushort*)sparse_out;

  // slice metadata lives in the recon region: written by topk_hist
  // (after the GEMM is done with xh/wh), consumed by rerank_slice/finish,
  // then the whole region is overwritten by decode at the end.
  int*   scnt_g = (int*)recon_out;                                  // [B*8]
  int*   slists = (int*)recon_out + (size_t)B_SZ * NSLICE;          // [B*8*64]
  float* cv     = (float*)((int*)recon_out +
                           (size_t)B_SZ * NSLICE * (1 + CAND_CAP)); // [B*64]

  // ws: tkv [B*30] f32, tki [B*30] i32, ccnt [B] i32, cidx [B*64] i32, dec_wT
  float* tkv    = (float*)d_ws;
  int*   tki    = (int*)((char*)d_ws + (size_t)B_SZ * K_TOP * 4);
  int*   ccnt   = (int*)((char*)d_ws + (size_t)2 * B_SZ * K_TOP * 4);
  int*   cidx   = (int*)((char*)d_ws + (size_t)B_SZ * (2 * K_TOP + 1) * 4);
  float* dec_wT = (float*)((char*)d_ws + (size_t)B_SZ * (2 * K_TOP + 1 + CAND_CAP) * 4);

  conv_xw<<<NXB + NWB, 256, 0, stream>>>(x, enc_w, dec_b, xh, wh);

  encode_gemm_bf16<<<dim3(F_SZ / GBN, B_SZ / GBM), 256, 0, stream>>>(xh, wh, enc_b,
                                                                     pre_h);

  topk_hist<<<B_SZ, 256, 0, stream>>>(pre_h, cidx, ccnt, scnt_g, slists);

  zero_sparse<<<8192, 256, 0, stream>>>((float4*)sparse_out);

  rerank_slice<<<(B_SZ / 4) * NSLICE, 256, 0, stream>>>(x, enc_w, enc_b, dec_b,
                                                        scnt_g, slists, cv);
  rerank_finish<<<B_SZ, 64, 0, stream>>>(cidx, ccnt, cv, sparse_out, tkv, tki);

  transpose_kernel<<<dim3(F_SZ / 32, D_SZ / 32), 256, 0, stream>>>(dec_w, dec_wT);
  decode_kernel<<<B_SZ, 256, 0, stream>>>(tkv, tki, dec_wT, dec_b, recon_out);
}

// Round 7
// 1401.996 us; speedup vs baseline: 1.0563x; 1.0563x over previous
//
#include <hip/hip_runtime.h>
#include <stdint.h>

#define B_SZ 16384
#define D_SZ 1024
#define F_SZ 8192
#define K_TOP 30
#define N_CAND 46     // histogram threshold rank (superset margin for exact rerank)
#define CAND_CAP 64   // max candidates kept per row
#define NBUCK 8192    // histogram bins
#define NSLICE 8      // feature slices (1024 features = 4 MB fp32 each = one XCD L2)

typedef short bf16x8 __attribute__((ext_vector_type(8)));
typedef ushort u16x8 __attribute__((ext_vector_type(8)));
typedef float f32x4 __attribute__((ext_vector_type(4)));
typedef uint32_t u32x4 __attribute__((ext_vector_type(4)));

// round-to-nearest-even float -> bf16 bits
__device__ __forceinline__ ushort f2bf(float f) {
  union { float f; uint32_t u; } a;
  a.f = f;
  const uint32_t r = a.u + 0x7fffu + ((a.u >> 16) & 1u);
  return (ushort)(r >> 16);
}

__device__ __forceinline__ float bf2f(ushort h) {
  union { uint32_t u; float f; } c;
  c.u = (uint32_t)h << 16;
  return c.f;
}

__device__ __forceinline__ void async16(const void* g, void* l) {
  __builtin_amdgcn_global_load_lds(
      (const __attribute__((address_space(1))) uint32_t*)g,
      (__attribute__((address_space(3))) uint32_t*)l, 16, 0, 0);
}

__device__ __forceinline__ void stnt4(void* p, float4 v) {
  union { float4 f; u32x4 u; } c;
  c.f = v;
  __builtin_nontemporal_store(c.u, (u32x4*)p);
}

// monotone value->bucket map: width 1/512 over [-8, 8]
__device__ __forceinline__ int bk(float f) {
  int k = (int)floorf(f * 512.f) + 4096;
  k = k < 0 ? 0 : k;
  return k > (NBUCK - 1) ? (NBUCK - 1) : k;
}

// ---------------------------------------------------------------------------
// Convert (x - dec_b) -> bf16 and enc_w -> bf16 in one launch.
// ---------------------------------------------------------------------------
#define NXB (B_SZ * D_SZ / 4 / 256)
#define NWB (F_SZ * D_SZ / 4 / 256)

__global__ __launch_bounds__(256) void conv_xw(const float* __restrict__ x,
                                               const float* __restrict__ w,
                                               const float* __restrict__ dec_b,
                                               ushort* __restrict__ xh,
                                               ushort* __restrict__ wh) {
  if (blockIdx.x < NXB) {
    const int i = blockIdx.x * 256 + threadIdx.x;
    const float4 v = ((const float4*)x)[i];
    const float4 db = ((const float4*)dec_b)[i & (D_SZ / 4 - 1)];
    ushort4 o;
    o.x = f2bf(v.x - db.x);
    o.y = f2bf(v.y - db.y);
    o.z = f2bf(v.z - db.z);
    o.w = f2bf(v.w - db.w);
    ((ushort4*)xh)[i] = o;
  } else {
    const int i = (blockIdx.x - NXB) * 256 + threadIdx.x;
    const float4 v = ((const float4*)w)[i];
    ushort4 o;
    o.x = f2bf(v.x);
    o.y = f2bf(v.y);
    o.z = f2bf(v.z);
    o.w = f2bf(v.w);
    ((ushort4*)wh)[i] = o;
  }
}

// ---------------------------------------------------------------------------
// Approx encode GEMM (bf16 MFMA), 128x128 tile, BK=64, DOUBLE-BUFFERED:
// one __syncthreads per K-tile; next tile's global_load_lds issued BEFORE
// the current tile's ds_read+MFMA so HBM latency hides under compute, and
// the barrier's implicit vmcnt(0) drain lands after the MFMA phase.
// Race-free: buffer b^1 was last read at tile kt-1 whose end-barrier
// (lgkmcnt(0)+vmcnt(0)) drained all reads and prior stages.
// Both-sides XOR chunk swizzle (verified conflict-free, R6: 0 conflicts).
// Epilogue transposes each wave's 64x64 C-subtile through LDS -> 16B stores.
// ---------------------------------------------------------------------------
#define GBM 128
#define GBN 128
#define GBK 64
#define NKT (D_SZ / GBK)   // 16 K-tiles
#define BUFH (GBM * GBK)   // 8192 ushorts per matrix per buffer
#define EPI_STRIDE 72      // 64 + 8 pad

__global__ __launch_bounds__(256) void encode_gemm_bf16(
    const ushort* __restrict__ A, const ushort* __restrict__ W,
    const float* __restrict__ enc_b, ushort* __restrict__ pre) {
  __shared__ ushort smem[4 * BUFH];  // 64 KB: buf b at b*16384 (As), +8192 (Bs)
  const int tid = threadIdx.x;
  const int wave = tid >> 6;
  const int lane = tid & 63;
  const int rb = blockIdx.y * GBM;
  const int cb = blockIdx.x * GBN;
  const int wm = (wave >> 1) * 64;
  const int wn = (wave & 1) * 64;

  // staging: thread t covers row r = (t>>3) + 32*i, chunk c = t&7 (16B).
  // source chunk inverse-swizzled: csrc = c ^ (r&7) (constant per thread).
  const int sr = tid >> 3;
  const int csrc = ((tid & 7) ^ (sr & 7)) * 8;
  const ushort* gA = A + (size_t)(rb + sr) * D_SZ + csrc;
  const ushort* gB = W + (size_t)(cb + sr) * D_SZ + csrc;

#define STAGE(kt, b)                                                        \
  do {                                                                      \
    const int ko = (kt) * GBK;                                              \
    ushort* dA = &smem[(b) * 2 * BUFH + wave * 512];                        \
    ushort* dB = &smem[(b) * 2 * BUFH + BUFH + wave * 512];                 \
    async16(gA + ko, dA);                                                   \
    async16(gB + ko, dB);                                                   \
    async16(gA + (size_t)32 * D_SZ + ko, dA + 2048);                        \
    async16(gB + (size_t)32 * D_SZ + ko, dB + 2048);                        \
    async16(gA + (size_t)64 * D_SZ + ko, dA + 4096);                        \
    async16(gB + (size_t)64 * D_SZ + ko, dB + 4096);                        \
    async16(gA + (size_t)96 * D_SZ + ko, dA + 6144);                        \
    async16(gB + (size_t)96 * D_SZ + ko, dB + 6144);                        \
  } while (0)

  f32x4 acc[4][4];
#pragma unroll
  for (int i = 0; i < 4; i++)
#pragma unroll
    for (int j = 0; j < 4; j++) acc[i][j] = (f32x4)(0.f);

  const int fm = lane & 15;
  const int kq = lane >> 4;  // k-quarter 0..3

  STAGE(0, 0);
  __syncthreads();  // vmcnt(0): tile 0 resident

  for (int kt = 0; kt < NKT; ++kt) {
    const int cbuf = kt & 1;
    if (kt + 1 < NKT) STAGE(kt + 1, cbuf ^ 1);  // issue early; lands under MFMA

    const ushort* Asb = &smem[cbuf * 2 * BUFH];
    const ushort* Bsb = &smem[cbuf * 2 * BUFH + BUFH];
#pragma unroll
    for (int kk = 0; kk < 2; kk++) {
      const int kc = (kk << 2) | kq;  // logical 16B chunk within row
      bf16x8 af[4], bfr[4];
#pragma unroll
      for (int i = 0; i < 4; i++) {
        const int row = wm + i * 16 + fm;
        af[i] = *(const bf16x8*)&Asb[row * GBK + (kc ^ (fm & 7)) * 8];
      }
#pragma unroll
      for (int j = 0; j < 4; j++) {
        const int row = wn + j * 16 + fm;
        bfr[j] = *(const bf16x8*)&Bsb[row * GBK + (kc ^ (fm & 7)) * 8];
      }
#pragma unroll
      for (int i = 0; i < 4; i++)
#pragma unroll
        for (int j = 0; j < 4; j++)
          acc[i][j] = __builtin_amdgcn_mfma_f32_16x16x32_bf16(af[i], bfr[j],
                                                              acc[i][j], 0, 0, 0);
    }
    __syncthreads();  // lgkm+vm drain AFTER compute: next tile ready
  }
#undef STAGE

  // ---- epilogue: LDS transpose -> contiguous bf16 rows, 16B stores ----
  float eb[4];
#pragma unroll
  for (int j = 0; j < 4; j++) eb[j] = enc_b[cb + wn + j * 16 + fm];

  ushort* epi = &smem[wave * 32 * EPI_STRIDE];  // 32 rows x 72 ushorts
  const int rg = lane >> 4;  // row group 0..3
  const int rr = lane & 31;
  const int cc = (lane >> 5) * 4;
#pragma unroll
  for (int p = 0; p < 2; p++) {
    // C layout: row_local = wm + (2p+i2)*16 + rg*4 + r, col_local = wn + j*16 + fm
#pragma unroll
    for (int i2 = 0; i2 < 2; i2++) {
      const int i = p * 2 + i2;
#pragma unroll
      for (int j = 0; j < 4; j++)
#pragma unroll
        for (int r = 0; r < 4; r++)
          epi[(i2 * 16 + rg * 4 + r) * EPI_STRIDE + j * 16 + fm] =
              f2bf(acc[i][j][r] + eb[j]);
    }
    // read back row-major; wave-private region (per-wave in-order DS pipe)
    ushort* gp = pre + (size_t)(rb + wm + p * 32 + rr) * F_SZ + cb + wn + cc * 8;
#pragma unroll
    for (int c = 0; c < 4; c++) {
      const u16x8 d = *(const u16x8*)&epi[rr * EPI_STRIDE + (cc + c) * 8];
      *(u16x8*)(gp + c * 8) = d;  // regular store: L2 merges full lines
    }
  }
}

// ---------------------------------------------------------------------------
// Histogram top-candidate select per row (bf16 pre input, now in workspace).
// ---------------------------------------------------------------------------
__global__ __launch_bounds__(256) void topk_hist(const ushort* __restrict__ pre,
                                                 int* __restrict__ cidx,
                                                 int* __restrict__ ccnt,
                                                 int* __restrict__ scnt_g,
                                                 int* __restrict__ slists) {
  __shared__ uint32_t hist[NBUCK];  // 32 KB
  __shared__ int scan[256];
  __shared__ int Tsh;
  __shared__ int cnt;
  __shared__ int cand[CAND_CAP];
  __shared__ int scnt_sh[NSLICE];
  const int b = blockIdx.x;
  const int t = threadIdx.x;
  const ushort* prow = pre + (size_t)b * F_SZ;

#pragma unroll
  for (int q = 0; q < NBUCK / 256; q++) hist[q * 256 + t] = 0;
  if (t == 0) cnt = 0;
  if (t < NSLICE) scnt_sh[t] = 0;
  __syncthreads();

  // row in registers: thread t holds ushort8 chunks (q*256+t), 32 values
  u16x8 v[4];
#pragma unroll
  for (int q = 0; q < 4; q++) v[q] = ((const u16x8*)prow)[q * 256 + t];

  int bki[32];
#pragma unroll
  for (int q = 0; q < 4; q++)
#pragma unroll
    for (int e = 0; e < 8; e++) bki[q * 8 + e] = bk(bf2f(v[q][e]));

#pragma unroll
  for (int i = 0; i < 32; i++) atomicAdd(&hist[bki[i]], 1u);
  __syncthreads();

  // thread t owns a descending 32-bucket chunk; partial sums + inclusive scan
  const int cbase = NBUCK - 32 * (t + 1);
  int s = 0;
#pragma unroll
  for (int j = 0; j < 32; j++) s += (int)hist[cbase + j];
  scan[t] = s;
  __syncthreads();
  for (int off = 1; off < 256; off <<= 1) {
    const int add = (t >= off) ? scan[t - off] : 0;
    __syncthreads();
    scan[t] += add;
    __syncthreads();
  }
  const int incl = scan[t];
  const int excl = incl - s;
  if (excl < N_CAND && incl >= N_CAND) {  // unique crossing thread
    int cum = excl;
    int T = cbase;
    for (int j = 31; j >= 0; j--) {
      cum += (int)hist[cbase + j];
      if (cum >= N_CAND) { T = cbase + j; break; }
    }
    Tsh = T;
  }
  __syncthreads();
  const int T = Tsh;

  // collect candidates >= threshold bucket
#pragma unroll
  for (int q = 0; q < 4; q++)
#pragma unroll
    for (int e = 0; e < 8; e++) {
      if (bki[q * 8 + e] >= T) {
        const int p = atomicAdd(&cnt, 1);
        if (p < CAND_CAP) cand[p] = (q * 256 + t) * 8 + e;
      }
    }
  __syncthreads();
  const int C = cnt < CAND_CAP ? cnt : CAND_CAP;
  if (t == 0) ccnt[b] = C;
  if (t < C) {
    const int f = cand[t];
    cidx[(size_t)b * CAND_CAP + t] = f;
    const int sl = f >> 10;  // feature slice (1024 features each)
    const int p = atomicAdd(&scnt_sh[sl], 1);
    slists[((size_t)b * NSLICE + sl) * CAND_CAP + p] = f | (t << 13);
  }
  __syncthreads();
  if (t < NSLICE) scnt_g[b * NSLICE + t] = scnt_sh[t];
}

// ---------------------------------------------------------------------------
// Sliced exact rerank + fused sparse zeroing. Block bid = q*8 + s handles
// rows 4q..4q+3 (one wave each), feature slice s; it also nt-zeros its own
// sparse chunk (rows 4q..4q+3, cols s*1024..+1023) -- zero writes overlap
// the gather-bound dot work, removing the standalone zero_sparse dispatch.
// ---------------------------------------------------------------------------
__global__ __launch_bounds__(256) void rerank_slice(
    const float* __restrict__ x, const float* __restrict__ enc_w,
    const float* __restrict__ enc_b, const float* __restrict__ dec_b,
    const int* __restrict__ scnt_g, const int* __restrict__ slists,
    float* __restrict__ sparse, float* __restrict__ cv) {
  const int q = blockIdx.x >> 3;
  const int s = blockIdx.x & 7;
  const int wave = threadIdx.x >> 6;
  const int lane = threadIdx.x & 63;
  const int r = q * 4 + wave;

  // zero this block's sparse chunk first (before any early exit)
  {
    const int zr = threadIdx.x >> 6;  // 0..3
    const int zc = threadIdx.x & 63;  // 0..63
    float4* rowp = (float4*)(sparse + (size_t)(q * 4 + zr) * F_SZ + s * 1024);
    const float4 z4 = make_float4(0.f, 0.f, 0.f, 0.f);
#pragma unroll
    for (int u = 0; u < 4; u++) stnt4(&rowp[u * 64 + zc], z4);
  }

  const int cell = r * NSLICE + s;
  const int n = scnt_g[cell];
  if (n == 0) return;

  // x row minus dec_b, lane-interleaved float4s: xr[j] = row float4 (j*64+lane)
  float4 xr[4];
  {
    const float4* xp = (const float4*)(x + (size_t)r * D_SZ);
    const float4* dp = (const float4*)dec_b;
#pragma unroll
    for (int j = 0; j < 4; j++) {
      const float4 xv = xp[j * 64 + lane];
      const float4 db = dp[j * 64 + lane];
      xr[j] = make_float4(xv.x - db.x, xv.y - db.y, xv.z - db.z, xv.w - db.w);
    }
  }

  const int base = cell * CAND_CAP;
  int k = 0;
  while (k < n) {
    const int e0 = slists[base + k];
    const bool two = (k + 1) < n;
    const int e1 = two ? slists[base + k + 1] : e0;
    const int f0 = e0 & 8191, g0 = e0 >> 13;
    const int f1 = e1 & 8191, g1 = e1 >> 13;
    const float4* w0 = (const float4*)(enc_w + (size_t)f0 * D_SZ);
    const float4* w1 = (const float4*)(enc_w + (size_t)f1 * D_SZ);
    float a0 = 0.f, a1 = 0.f;
#pragma unroll
    for (int j = 0; j < 4; j++) {
      const float4 u = w0[j * 64 + lane];
      const float4 p = xr[j];
      a0 += u.x * p.x + u.y * p.y + u.z * p.z + u.w * p.w;
    }
#pragma unroll
    for (int j = 0; j < 4; j++) {
      const float4 u = w1[j * 64 + lane];
      const float4 p = xr[j];
      a1 += u.x * p.x + u.y * p.y + u.z * p.z + u.w * p.w;
    }
#pragma unroll
    for (int off = 32; off > 0; off >>= 1) {
      a0 += __shfl_xor(a0, off);
      a1 += __shfl_xor(a1, off);
    }
    if (lane == 0) {
      cv[(size_t)r * CAND_CAP + g0] = a0 + enc_b[f0];
      if (two) cv[(size_t)r * CAND_CAP + g1] = a1 + enc_b[f1];
    }
    k += 2;
  }
}

// ---------------------------------------------------------------------------
// Selection: one wave per row, bitonic sort 64 (value desc, idx asc), write
// top-30 + scatter relu'd exact values into sparse.
// ---------------------------------------------------------------------------
__global__ __launch_bounds__(64) void rerank_finish(
    const int* __restrict__ cidx, const int* __restrict__ ccnt,
    const float* __restrict__ cv, float* __restrict__ sparse,
    float* __restrict__ tkv, int* __restrict__ tki) {
  const int b = blockIdx.x;
  const int t = threadIdx.x;
  const int C = ccnt[b];
  float v = (t < C) ? cv[(size_t)b * CAND_CAP + t] : -__builtin_inff();
  int id = (t < C) ? cidx[(size_t)b * CAND_CAP + t] : 0x7fffffff;
#pragma unroll
  for (int k = 2; k <= 64; k <<= 1) {
#pragma unroll
    for (int j = k >> 1; j > 0; j >>= 1) {
      const float ov = __shfl_xor(v, j);
      const int oi = __shfl_xor(id, j);
      const bool up = (t & k) == 0;       // this block sorts best-first
      const bool lower = (t & j) == 0;    // lane is lower index of the pair
      const bool ob = (ov > v) || (ov == v && oi < id);  // other is better
      if ((lower == up) ? ob : !ob) { v = ov; id = oi; }
    }
  }
  if (t < K_TOP) {
    const float rv = v > 0.f ? v : 0.f;
    tkv[(size_t)b * K_TOP + t] = rv;
    tki[(size_t)b * K_TOP + t] = id;
    sparse[(size_t)b * F_SZ + id] = rv;
  }
}

// ---------------------------------------------------------------------------
// Transpose dec_w [D, F] -> dec_wT [F, D]
// ---------------------------------------------------------------------------
__global__ __launch_bounds__(256) void transpose_kernel(const float* __restrict__ in,
                                                        float* __restrict__ out) {
  __shared__ float tile[32][33];
  const int bx = blockIdx.x * 32;
  const int by = blockIdx.y * 32;
  const int tx = threadIdx.x & 31;
  const int ty = threadIdx.x >> 5;
#pragma unroll
  for (int r = 0; r < 32; r += 8)
    tile[ty + r][tx] = in[(size_t)(by + ty + r) * F_SZ + bx + tx];
  __syncthreads();
#pragma unroll
  for (int r = 0; r < 32; r += 8)
    out[(size_t)(bx + ty + r) * D_SZ + by + tx] = tile[tx][ty + r];
}

// ---------------------------------------------------------------------------
// Decode, XCD-sliced: block bid = g*8 + s computes rows g*8..g*8+7, columns
// s*128..s*128+127 -> 4 MB resident working set per XCD L2.
// ---------------------------------------------------------------------------
__global__ __launch_bounds__(256) void decode_kernel(const float* __restrict__ tkv,
                                                     const int* __restrict__ tki,
                                                     const float* __restrict__ dec_wT,
                                                     const float* __restrict__ dec_b,
                                                     float* __restrict__ recon) {
  __shared__ float kv[8][32];
  __shared__ int ki[8][32];
  const int g = blockIdx.x >> 3;
  const int s = blockIdx.x & 7;
  const int t = threadIdx.x;
  if (t < 8 * K_TOP) {
    const int rr = t / K_TOP;
    const int kk = t - rr * K_TOP;
    kv[rr][kk] = tkv[(size_t)(g * 8 + rr) * K_TOP + kk];
    ki[rr][kk] = tki[(size_t)(g * 8 + rr) * K_TOP + kk];
  }
  __syncthreads();
  const int rr = t >> 5;                 // 0..7 (row within group)
  const int col = s * 128 + (t & 31) * 4;
  const int b = g * 8 + rr;
  float4 acc = *(const float4*)&dec_b[col];
#pragma unroll 5
  for (int k = 0; k < K_TOP; k++) {
    const float v = kv[rr][k];
    const float4 w = *(const float4*)&dec_wT[(size_t)ki[rr][k] * D_SZ + col];
    acc.x += v * w.x; acc.y += v * w.y; acc.z += v * w.z; acc.w += v * w.w;
  }
  stnt4(&recon[(size_t)b * D_SZ + col], acc);
}

// ---------------------------------------------------------------------------
extern "C" void kernel_launch(void* const* d_in, const int* in_sizes, int n_in,
                              void* d_out, int out_size, void* d_ws, size_t ws_size,
                              hipStream_t stream) {
  const float* x     = (const float*)d_in[0];  // [B, D]
  const float* enc_w = (const float*)d_in[1];  // [F, D]
  const float* enc_b = (const float*)d_in[2];  // [F]
  const float* dec_w = (const float*)d_in[3];  // [D, F]
  const float* dec_b = (const float*)d_in[4];  // [D]

  float* recon_out  = (float*)d_out;                        // [B, D]
  float* sparse_out = (float*)d_out + (size_t)B_SZ * D_SZ;  // [B, F]

  // bf16 limbs live in the recon region (dead until decode, which runs last)
  ushort* xh = (ushort*)recon_out;        // [B, D] bf16 (32 MB)
  ushort* wh = xh + (size_t)B_SZ * D_SZ;  // [F, D] bf16 (16 MB)

  // slice metadata lives in the recon region: written by topk_hist
  // (after the GEMM is done with xh/wh), consumed by rerank_slice/finish,
  // then the whole region is overwritten by decode at the end.
  int*   scnt_g = (int*)recon_out;                                  // [B*8]
  int*   slists = (int*)recon_out + (size_t)B_SZ * NSLICE;          // [B*8*64]
  float* cv     = (float*)((int*)recon_out +
                           (size_t)B_SZ * NSLICE * (1 + CAND_CAP)); // [B*64]

  // ws: tkv, tki, ccnt, cidx, dec_wT, then bf16 pre (256 MB) -- pre no
  // longer aliases sparse_out, so sparse zeroing is fused into rerank_slice.
  float*  tkv    = (float*)d_ws;
  int*    tki    = (int*)((char*)d_ws + (size_t)B_SZ * K_TOP * 4);
  int*    ccnt   = (int*)((char*)d_ws + (size_t)2 * B_SZ * K_TOP * 4);
  int*    cidx   = (int*)((char*)d_ws + (size_t)B_SZ * (2 * K_TOP + 1) * 4);
  float*  dec_wT = (float*)((char*)d_ws + (size_t)B_SZ * (2 * K_TOP + 1 + CAND_CAP) * 4);
  ushort* pre_h  = (ushort*)(dec_wT + (size_t)F_SZ * D_SZ);

  conv_xw<<<NXB + NWB, 256, 0, stream>>>(x, enc_w, dec_b, xh, wh);

  encode_gemm_bf16<<<dim3(F_SZ / GBN, B_SZ / GBM), 256, 0, stream>>>(xh, wh, enc_b,
                                                                     pre_h);

  topk_hist<<<B_SZ, 256, 0, stream>>>(pre_h, cidx, ccnt, scnt_g, slists);

  rerank_slice<<<(B_SZ / 4) * NSLICE, 256, 0, stream>>>(x, enc_w, enc_b, dec_b,
                                                        scnt_g, slists,
                                                        sparse_out, cv);
  rerank_finish<<<B_SZ, 64, 0, stream>>>(cidx, ccnt, cv, sparse_out, tkv, tki);

  transpose_kernel<<<dim3(F_SZ / 32, D_SZ / 32), 256, 0, stream>>>(dec_w, dec_wT);
  decode_kernel<<<B_SZ, 256, 0, stream>>>(tkv, tki, dec_wT, dec_b, recon_out);
}